// Round 1
// baseline (127.499 us; speedup 1.0000x reference)
//
#include <hip/hip_runtime.h>

// DTW loss: sum |preds[b, path_i[b,p]] - targets[b, path_j[b,p]]|_1 / (B*S)
// B=256, S=8192, P=16383. preds/targets fp32 (B,S,2); path_* int32 (B,P).
// Memory-bound: ~67 MB ideal HBM traffic -> ~10.6 us floor at 6.3 TB/s.

#define BB 256
#define SS 8192
#define PP 16383
#define QCH 4096   // pairs handled per block (4 blocks per batch)

__global__ void dtw_zero_kernel(float* out) { out[0] = 0.0f; }

__global__ __launch_bounds__(256) void dtw_loss_kernel(
    const float* __restrict__ preds,
    const float* __restrict__ targets,
    const int* __restrict__ path_i,
    const int* __restrict__ path_j,
    float* __restrict__ out)
{
    // XCD-affinity swizzle: batch b -> XCD (b % 8). Consecutive blockIdx
    // round-robin across the 8 XCDs, so invert that mapping: all 4 chunks of a
    // batch land on the same XCD -> its 128 KB gather window fetched into ONE L2.
    const int xcd     = blockIdx.x & 7;    // 0..7
    const int slot    = blockIdx.x >> 3;   // 0..127
    const int batch   = xcd + 8 * (slot >> 2);  // 0..255, batch%8 == xcd
    const int quarter = slot & 3;          // 0..3

    const float2* __restrict__ p2 = (const float2*)preds   + (size_t)batch * SS;
    const float2* __restrict__ t2 = (const float2*)targets + (size_t)batch * SS;
    const int*    __restrict__ pi = path_i + (size_t)batch * PP + quarter * QCH;
    const int*    __restrict__ pj = path_j + (size_t)batch * PP + quarter * QCH;
    const int n = min(PP - quarter * QCH, QCH);  // 4096, or 4095 for quarter 3

    float acc = 0.0f;
    if (n == QCH) {
        // Common path: fully unrolled -> 16 independent index->gather chains
        // in flight per thread to hide L2/HBM gather latency.
        #pragma unroll
        for (int u = 0; u < QCH / 256; ++u) {
            const int k = u * 256 + threadIdx.x;
            const int i = pi[k];
            const int j = pj[k];
            const float2 a = p2[i];
            const float2 b = t2[j];
            acc += fabsf(a.x - b.x) + fabsf(a.y - b.y);
        }
    } else {
        for (int k = threadIdx.x; k < n; k += 256) {
            const int i = pi[k];
            const int j = pj[k];
            const float2 a = p2[i];
            const float2 b = t2[j];
            acc += fabsf(a.x - b.x) + fabsf(a.y - b.y);
        }
    }

    // Wave (64-lane) shuffle reduction
    #pragma unroll
    for (int off = 32; off > 0; off >>= 1)
        acc += __shfl_down(acc, off, 64);

    __shared__ float wsum[4];
    const int lane = threadIdx.x & 63;
    const int wid  = threadIdx.x >> 6;
    if (lane == 0) wsum[wid] = acc;
    __syncthreads();
    if (threadIdx.x == 0) {
        const float s = wsum[0] + wsum[1] + wsum[2] + wsum[3];
        // scale 1/(B*S) = 2^-21, exact in fp32
        atomicAdd(out, s * (1.0f / ((float)BB * (float)SS)));
    }
}

extern "C" void kernel_launch(void* const* d_in, const int* in_sizes, int n_in,
                              void* d_out, int out_size, void* d_ws, size_t ws_size,
                              hipStream_t stream) {
    const float* preds   = (const float*)d_in[0];
    const float* targets = (const float*)d_in[1];
    const int*   path_i  = (const int*)d_in[2];
    const int*   path_j  = (const int*)d_in[3];
    float* out = (float*)d_out;

    // d_out is poisoned 0xAA before every launch -> zero it first (stream-ordered).
    dtw_zero_kernel<<<1, 1, 0, stream>>>(out);

    const int blocks = BB * 4;  // 1024 blocks, 4 per batch
    dtw_loss_kernel<<<blocks, 256, 0, stream>>>(preds, targets, path_i, path_j, out);
}